// Round 1
// baseline (1149.044 us; speedup 1.0000x reference)
//
#include <hip/hip_runtime.h>
#include <math.h>

#define NCOL 256
#define NSEG 16

__device__ __forceinline__ unsigned f2u_ord(float f) {
    unsigned u = __float_as_uint(f);
    return (u & 0x80000000u) ? ~u : (u | 0x80000000u);
}
__device__ __forceinline__ float u2f_ord(unsigned u) {
    unsigned b = (u & 0x80000000u) ? (u ^ 0x80000000u) : ~u;
    return __uint_as_float(b);
}

// K0: zero the cross-kernel accumulators (ws is re-poisoned 0xAA before every call)
__global__ void k0_init(unsigned* segmax, float* segsum, float* Z, float* W) {
    int t = threadIdx.x;
    if (t < NSEG) { segmax[t] = 0u; segsum[t] = 0.f; }
    if (t == NSEG)     *Z = 0.f;
    if (t == NSEG + 1) *W = 0.f;
}

// K1: per-row dots (one wave per row, lane j owns cols 4j..4j+3) + segment max
__global__ __launch_bounds__(256) void k1_dots(
    const float* __restrict__ feats, const int* __restrict__ segid,
    const float* __restrict__ wl, const float* __restrict__ blp,
    const float* __restrict__ wg, const float* __restrict__ bgp,
    float* __restrict__ l_out, float* __restrict__ g_out,
    unsigned* __restrict__ segmax_g, int rowsPerBlock, int n) {
    __shared__ unsigned smax[NSEG];
    int tid = threadIdx.x;
    if (tid < NSEG) smax[tid] = 0u;
    __syncthreads();
    int lane = tid & 63, wave = tid >> 6;
    int row0 = blockIdx.x * rowsPerBlock;
    int row1 = min(row0 + rowsPerBlock, n);
    float4 wl4 = ((const float4*)wl)[lane];
    float4 wg4 = ((const float4*)wg)[lane];
    float bl = blp[0], bg = bgp[0];
    for (int row = row0 + wave; row < row1; row += 4) {
        float4 x = ((const float4*)(feats + (size_t)row * NCOL))[lane];
        float dl = x.x * wl4.x + x.y * wl4.y + x.z * wl4.z + x.w * wl4.w;
        float dg = x.x * wg4.x + x.y * wg4.y + x.z * wg4.z + x.w * wg4.w;
        for (int m = 32; m; m >>= 1) {
            dl += __shfl_xor(dl, m, 64);
            dg += __shfl_xor(dg, m, 64);
        }
        if (lane == 0) {
            float g = dg + bg;
            l_out[row] = dl + bl;
            g_out[row] = g;
            atomicMax(&smax[segid[row]], f2u_ord(g));
        }
    }
    __syncthreads();
    if (tid < NSEG && smax[tid] != 0u) atomicMax(&segmax_g[tid], smax[tid]);
}

// K2: ex = exp(g - segmax), segment sums (run-length flush: ids are sorted)
__global__ __launch_bounds__(256) void k2_exp(
    const float* __restrict__ g, const int* __restrict__ segid,
    const unsigned* __restrict__ segmax_g, float* __restrict__ ex_out,
    float* __restrict__ segsum_g, int perBlock, int n) {
    __shared__ float ssum[NSEG];
    __shared__ float smax_f[NSEG];
    int tid = threadIdx.x;
    if (tid < NSEG) { ssum[tid] = 0.f; smax_f[tid] = u2f_ord(segmax_g[tid]); }
    __syncthreads();
    int i0 = blockIdx.x * perBlock;
    int i1 = min(i0 + perBlock, n);
    int curSeg = -1;
    float acc = 0.f;
    for (int i = i0 + tid; i < i1; i += blockDim.x) {
        int s = segid[i];
        float e = expf(g[i] - smax_f[s]);
        ex_out[i] = e;
        if (s != curSeg) {
            if (curSeg >= 0) atomicAdd(&ssum[curSeg], acc);
            curSeg = s; acc = 0.f;
        }
        acc += e;
    }
    if (curSeg >= 0) atomicAdd(&ssum[curSeg], acc);
    __syncthreads();
    if (tid < NSEG && ssum[tid] != 0.f) atomicAdd(&segsum_g[tid], ssum[tid]);
}

// K3: w = sigmoid(l) * ex/segsum; Z = sum(w)
__global__ __launch_bounds__(256) void k3_weights(
    const float* __restrict__ l, const float* __restrict__ ex,
    const int* __restrict__ segid, const float* __restrict__ segsum_g,
    float* __restrict__ w_out, float* __restrict__ Z_g, int perBlock, int n) {
    __shared__ float ssum_s[NSEG];
    int tid = threadIdx.x;
    if (tid < NSEG) ssum_s[tid] = segsum_g[tid];
    __syncthreads();
    int i0 = blockIdx.x * perBlock;
    int i1 = min(i0 + perBlock, n);
    float acc = 0.f;
    for (int i = i0 + tid; i < i1; i += blockDim.x) {
        float soft = ex[i] / ssum_s[segid[i]];
        float sig = 1.f / (1.f + expf(-l[i]));
        float w = sig * soft;
        w_out[i] = w;
        acc += w;
    }
    for (int m = 32; m; m >>= 1) acc += __shfl_xor(acc, m, 64);
    __shared__ float la[4];
    int lane = tid & 63, wave = tid >> 6;
    if (lane == 0) la[wave] = acc;
    __syncthreads();
    if (tid == 0) atomicAdd(Z_g, la[0] + la[1] + la[2] + la[3]);
}

// K4: per-column weighted sums S1 = sum(w*x), S2 = sum(w*x^2) -> per-block partials
__global__ __launch_bounds__(256) void k4_colsums(
    const float* __restrict__ feats, const float* __restrict__ w,
    const float* __restrict__ Z_g, float* __restrict__ part,
    float* __restrict__ W_g, int rowsPerBlock, int n) {
    int tid = threadIdx.x;
    int lane = tid & 63, wave = tid >> 6;
    int row0 = blockIdx.x * rowsPerBlock;
    int row1 = min(row0 + rowsPerBlock, n);
    float Z = Z_g[0];
    float4 a1 = {0.f, 0.f, 0.f, 0.f};
    float4 a2 = {0.f, 0.f, 0.f, 0.f};
    float wsum = 0.f;
    for (int row = row0 + wave; row < row1; row += 4) {
        float wr = w[row] / Z;   // matches reference's explicit divide
        float4 x = ((const float4*)(feats + (size_t)row * NCOL))[lane];
        a1.x += wr * x.x; a1.y += wr * x.y; a1.z += wr * x.z; a1.w += wr * x.w;
        a2.x += wr * x.x * x.x; a2.y += wr * x.y * x.y;
        a2.z += wr * x.z * x.z; a2.w += wr * x.w * x.w;
        if (lane == 0) wsum += wr;
    }
    __shared__ float lds1[4][NCOL];
    __shared__ float lds2[4][NCOL];
    __shared__ float lw[4];
    ((float4*)lds1[wave])[lane] = a1;
    ((float4*)lds2[wave])[lane] = a2;
    if (lane == 0) lw[wave] = wsum;
    __syncthreads();
    if (tid < NCOL) {
        float s1 = lds1[0][tid] + lds1[1][tid] + lds1[2][tid] + lds1[3][tid];
        float s2 = lds2[0][tid] + lds2[1][tid] + lds2[2][tid] + lds2[3][tid];
        size_t base = (size_t)blockIdx.x * (2 * NCOL);
        part[base + tid] = s1;
        part[base + NCOL + tid] = s2;
    }
    if (tid == 0) atomicAdd(W_g, lw[0] + lw[1] + lw[2] + lw[3]);
}

// K4b: reduce partials -> mean[c], istd[c]
__global__ __launch_bounds__(1024) void k4b_finalize(
    const float* __restrict__ part, const float* __restrict__ W_g,
    float* __restrict__ mean_out, float* __restrict__ istd_out, int nb) {
    __shared__ float red[4][2 * NCOL];
    int tid = threadIdx.x;
    int q = tid >> 8;        // 0..3
    int c = tid & 255;
    int bq = nb >> 2;
    int b0 = q * bq, b1 = (q == 3) ? nb : (q + 1) * bq;
    float s1 = 0.f, s2 = 0.f;
    for (int b = b0; b < b1; b++) {
        size_t base = (size_t)b * (2 * NCOL);
        s1 += part[base + c];
        s2 += part[base + NCOL + c];
    }
    red[q][c] = s1;
    red[q][NCOL + c] = s2;
    __syncthreads();
    if (tid < NCOL) {
        float S1 = red[0][tid] + red[1][tid] + red[2][tid] + red[3][tid];
        float S2 = red[0][NCOL + tid] + red[1][NCOL + tid] +
                   red[2][NCOL + tid] + red[3][NCOL + tid];
        float W = W_g[0];
        float m = S1 / W;
        float v = S2 - 2.f * m * S1 + m * m * W;
        mean_out[tid] = m;
        istd_out[tid] = 1.0f / sqrtf(v);
    }
}

// K5: out = (x - mean) * istd   (stride % 64 == 0 so each thread's col group is fixed)
__global__ __launch_bounds__(256) void k5_norm(
    const float* __restrict__ feats, const float* __restrict__ mean,
    const float* __restrict__ istd, float* __restrict__ out, size_t nvec) {
    size_t tid = (size_t)blockIdx.x * blockDim.x + threadIdx.x;
    size_t stride = (size_t)gridDim.x * blockDim.x;
    int c4 = (int)(tid & 63);
    float4 m4 = ((const float4*)mean)[c4];
    float4 s4 = ((const float4*)istd)[c4];
    const float4* in = (const float4*)feats;
    float4* o = (float4*)out;
    for (size_t i = tid; i < nvec; i += stride) {
        float4 x = in[i];
        float4 r;
        r.x = (x.x - m4.x) * s4.x;
        r.y = (x.y - m4.y) * s4.y;
        r.z = (x.z - m4.z) * s4.z;
        r.w = (x.w - m4.w) * s4.w;
        o[i] = r;
    }
}

extern "C" void kernel_launch(void* const* d_in, const int* in_sizes, int n_in,
                              void* d_out, int out_size, void* d_ws, size_t ws_size,
                              hipStream_t stream) {
    const float* feats = (const float*)d_in[0];
    const int*   segid = (const int*)d_in[1];
    const float* wl    = (const float*)d_in[2];
    const float* bl    = (const float*)d_in[3];
    const float* wg    = (const float*)d_in[4];
    const float* bg    = (const float*)d_in[5];
    float* out = (float*)d_out;

    const int n = in_sizes[1];          // 500000 rows

    // workspace layout (4-byte units)
    float* ws = (float*)d_ws;
    float*    l_buf  = ws;                          // n
    float*    g_buf  = ws + (size_t)n;              // n
    float*    ex_buf = ws + 2 * (size_t)n;          // n
    float*    w_buf  = ws + 3 * (size_t)n;          // n
    unsigned* segmax = (unsigned*)(ws + 4 * (size_t)n);  // 16
    float*    segsum = ws + 4 * (size_t)n + 16;     // 16
    float*    Z_g    = ws + 4 * (size_t)n + 32;     // 1
    float*    W_g    = ws + 4 * (size_t)n + 33;     // 1
    float*    mean_b = ws + 4 * (size_t)n + 64;     // 256
    float*    istd_b = ws + 4 * (size_t)n + 320;    // 256
    float*    part   = ws + 4 * (size_t)n + 576;    // NB4 * 512

    const int NB1 = 2048;
    const int NB2 = 512;
    const int NB4 = 1024;
    const int NB5 = 2048;
    int rpb1 = (n + NB1 - 1) / NB1;
    int pb2  = (n + NB2 - 1) / NB2;
    int rpb4 = (n + NB4 - 1) / NB4;
    size_t nvec = (size_t)n * (NCOL / 4);

    k0_init<<<1, 64, 0, stream>>>(segmax, segsum, Z_g, W_g);
    k1_dots<<<NB1, 256, 0, stream>>>(feats, segid, wl, bl, wg, bg,
                                     l_buf, g_buf, segmax, rpb1, n);
    k2_exp<<<NB2, 256, 0, stream>>>(g_buf, segid, segmax, ex_buf, segsum, pb2, n);
    k3_weights<<<NB2, 256, 0, stream>>>(l_buf, ex_buf, segid, segsum, w_buf, Z_g, pb2, n);
    k4_colsums<<<NB4, 256, 0, stream>>>(feats, w_buf, Z_g, part, W_g, rpb4, n);
    k4b_finalize<<<1, 1024, 0, stream>>>(part, W_g, mean_b, istd_b, NB4);
    k5_norm<<<NB5, 256, 0, stream>>>(feats, mean_b, istd_b, out, nvec);
}